// Round 3
// baseline (1695.982 us; speedup 1.0000x reference)
//
#include <hip/hip_runtime.h>
#include <hip/hip_bf16.h>
#include <math.h>

// Problem constants
#define L_SEQ   1024
#define DMODEL  1024
#define DINNER  2048
#define DSTATE  16
#define DCONV   4
#define NPROJ   (DINNER + 4 * DSTATE)   // 2112

__device__ __forceinline__ float softplus_f(float v) {
    // jax.nn.softplus = logaddexp(v, 0) = max(v,0) + log1p(exp(-|v|))
    return fmaxf(v, 0.f) + log1pf(expf(-fabsf(v)));
}
__device__ __forceinline__ float silu_f(float v) {
    return v / (1.f + expf(-v));
}

// -------- Generic tiled f32 GEMM: C[M,N] = A[M,K(lda)] @ W[N,K]^T (+bias,epi) ----
// BM=BN=64, BK=16, TM=TN=4, 256 threads.
// EPI: 0 = plain store, 1 = softplus(acc + bias[col])
template<int EPI>
__global__ __launch_bounds__(256) void gemm_tn_64(
    const float* __restrict__ A, const float* __restrict__ W,
    const float* __restrict__ bias, float* __restrict__ C,
    int M, int N, int K, int lda)
{
    __shared__ float As[16][64];
    __shared__ float Ws[16][64];
    const int tid = threadIdx.x;
    const int tx = tid & 15;        // N direction
    const int ty = tid >> 4;        // M direction
    const int row0 = blockIdx.y * 64;
    const int col0 = blockIdx.x * 64;

    float acc[4][4] = {};

    for (int k0 = 0; k0 < K; k0 += 16) {
        #pragma unroll
        for (int i = 0; i < 4; ++i) {
            int idx = tid + i * 256;     // 0..1023
            int m = idx >> 4;            // tile row 0..63
            int k = idx & 15;            // tile k 0..15
            As[k][m] = A[(size_t)(row0 + m) * lda + (k0 + k)];
            Ws[k][m] = W[(size_t)(col0 + m) * K   + (k0 + k)];
        }
        __syncthreads();
        #pragma unroll
        for (int k = 0; k < 16; ++k) {
            float4 a4 = *reinterpret_cast<const float4*>(&As[k][ty * 4]);
            float4 w4 = *reinterpret_cast<const float4*>(&Ws[k][tx * 4]);
            float av[4] = {a4.x, a4.y, a4.z, a4.w};
            float wv[4] = {w4.x, w4.y, w4.z, w4.w};
            #pragma unroll
            for (int i = 0; i < 4; ++i)
                #pragma unroll
                for (int j = 0; j < 4; ++j)
                    acc[i][j] = fmaf(av[i], wv[j], acc[i][j]);
        }
        __syncthreads();
    }

    #pragma unroll
    for (int i = 0; i < 4; ++i) {
        int row = row0 + ty * 4 + i;
        #pragma unroll
        for (int j = 0; j < 4; ++j) {
            int col = col0 + tx * 4 + j;
            float v = acc[i][j];
            if (EPI == 1) {
                v += bias[col];
                v = softplus_f(v);
            }
            C[(size_t)row * N + col] = v;
        }
    }
}

// -------- Depthwise causal conv (k=4) + bias + SiLU ------------------------------
// xz layout: (L, 4096); xc = xz[:, 0:2048]. Output u: (L, 2048)
__global__ __launch_bounds__(256) void conv_silu_kernel(
    const float* __restrict__ xz, const float* __restrict__ cw,
    const float* __restrict__ cb, float* __restrict__ u)
{
    int idx = blockIdx.x * 256 + threadIdx.x;   // L*DINNER threads
    int l = idx >> 11;           // /2048
    int d = idx & (DINNER - 1);
    float acc = cb[d];
    #pragma unroll
    for (int k = 0; k < DCONV; ++k) {
        int ls = l - (DCONV - 1) + k;
        float xv = (ls >= 0) ? xz[(size_t)ls * (2 * DINNER) + d] : 0.f;
        acc = fmaf(xv, cw[d * DCONV + k], acc);
    }
    u[idx] = silu_f(acc);
}

// -------- Sequential complex SSM scan --------------------------------------------
// One thread per (d, n): 64-thread blocks = 4 d-channels x 16 states.
// H[l] = (2+dt*A)/(2-dt*A) * H[l-1] + (2*dt/(2-dt*A)) * B[l] * u[l]
// y[l,d] = (sum_n Re(C[l,n]*H[l,d,n]) + D[d]*u[l,d]) * silu(z[l,d])
__global__ __launch_bounds__(64) void scan_kernel(
    const float* __restrict__ delta, const float* __restrict__ ssm,
    const float* __restrict__ u, const float* __restrict__ xz,
    const float* __restrict__ A_log_re, const float* __restrict__ A_log_im,
    const float* __restrict__ Dvec, float* __restrict__ y)
{
    const int tid  = threadIdx.x;
    const int n    = tid & 15;
    const int dloc = tid >> 4;            // 0..3
    const int d    = blockIdx.x * 4 + dloc;

    const float alre = A_log_re[d * DSTATE + n];
    const float alim = A_log_im[d * DSTATE + n];
    const float mag  = expf(alre);
    const float a_re = -mag * cosf(alim);
    const float a_im = -mag * sinf(alim);
    const float Dd   = Dvec[d];

    float h_re = 0.f, h_im = 0.f;

    // current-step values (l = 0)
    float dt = delta[d];
    float uv = u[d];
    float br = ssm[DINNER + n];
    float bi = ssm[DINNER + DSTATE + n];
    float cr = ssm[DINNER + 2 * DSTATE + n];
    float ci = ssm[DINNER + 3 * DSTATE + n];

    for (int l = 0; l < L_SEQ; ++l) {
        // prefetch next step
        float dt_n = 0.f, uv_n = 0.f, br_n = 0.f, bi_n = 0.f, cr_n = 0.f, ci_n = 0.f;
        if (l + 1 < L_SEQ) {
            size_t ro = (size_t)(l + 1);
            dt_n = delta[ro * DINNER + d];
            uv_n = u[ro * DINNER + d];
            const float* srow = ssm + ro * NPROJ;
            br_n = srow[DINNER + n];
            bi_n = srow[DINNER + DSTATE + n];
            cr_n = srow[DINNER + 2 * DSTATE + n];
            ci_n = srow[DINNER + 3 * DSTATE + n];
        }

        // bilinear transform coefficients
        float dta_re = dt * a_re, dta_im = dt * a_im;
        float den_re = 2.f - dta_re, den_im = -dta_im;
        float num_re = 2.f + dta_re, num_im = dta_im;
        float inv = 1.f / (den_re * den_re + den_im * den_im);
        // A_bar = num * conj(den) * inv
        float ab_re = (num_re * den_re + num_im * den_im) * inv;
        float ab_im = (num_im * den_re - num_re * den_im) * inv;
        // coef = 2*dt * conj(den) * inv
        float t = 2.f * dt * inv;
        float co_re =  t * den_re;
        float co_im = -t * den_im;
        // u_bar = coef * B * u
        float cbr = co_re * br - co_im * bi;
        float cbi = co_re * bi + co_im * br;
        float ub_re = cbr * uv;
        float ub_im = cbi * uv;
        // H update
        float hr = ab_re * h_re - ab_im * h_im + ub_re;
        float hi = ab_re * h_im + ab_im * h_re + ub_im;
        h_re = hr; h_im = hi;
        // contribution Re(C * H)
        float contrib = cr * h_re - ci * h_im;
        contrib += __shfl_xor(contrib, 1, 16);
        contrib += __shfl_xor(contrib, 2, 16);
        contrib += __shfl_xor(contrib, 4, 16);
        contrib += __shfl_xor(contrib, 8, 16);
        if (n == 0) {
            float zv = xz[(size_t)l * (2 * DINNER) + DINNER + d];
            float yv = contrib + Dd * uv;
            y[(size_t)l * DINNER + d] = yv * silu_f(zv);
        }

        dt = dt_n; uv = uv_n; br = br_n; bi = bi_n; cr = cr_n; ci = ci_n;
    }
}

extern "C" void kernel_launch(void* const* d_in, const int* in_sizes, int n_in,
                              void* d_out, int out_size, void* d_ws, size_t ws_size,
                              hipStream_t stream)
{
    const float* x         = (const float*)d_in[0];   // (1, L, DMODEL)
    const float* in_proj_w = (const float*)d_in[1];   // (2*DINNER, DMODEL)
    const float* conv_w    = (const float*)d_in[2];   // (DINNER, 1, DCONV)
    const float* conv_b    = (const float*)d_in[3];   // (DINNER,)
    const float* x_proj_w  = (const float*)d_in[4];   // (NPROJ, DINNER)
    const float* dt_proj_w = (const float*)d_in[5];   // (DINNER, DINNER)
    const float* dt_proj_b = (const float*)d_in[6];   // (DINNER,)
    const float* A_log_re  = (const float*)d_in[7];   // (DINNER, DSTATE)
    const float* A_log_im  = (const float*)d_in[8];   // (DINNER, DSTATE)
    const float* Dvec      = (const float*)d_in[9];   // (DINNER,)
    const float* out_proj_w= (const float*)d_in[10];  // (DMODEL, DINNER)
    float* out = (float*)d_out;                       // (1, L, DMODEL)

    float* ws    = (float*)d_ws;
    float* xz    = ws;                                   // L * 4096
    float* u     = xz    + (size_t)L_SEQ * 2 * DINNER;   // L * 2048
    float* ssm   = u     + (size_t)L_SEQ * DINNER;       // L * 2112
    float* delta = ssm   + (size_t)L_SEQ * NPROJ;        // L * 2048
    float* y     = delta + (size_t)L_SEQ * DINNER;       // L * 2048

    // 1) xz = x @ in_proj_w.T      (1024 x 4096, K=1024)
    gemm_tn_64<0><<<dim3((2 * DINNER) / 64, L_SEQ / 64), 256, 0, stream>>>(
        x, in_proj_w, nullptr, xz, L_SEQ, 2 * DINNER, DMODEL, DMODEL);

    // 2) depthwise causal conv + SiLU -> u   (1024 x 2048)
    conv_silu_kernel<<<(L_SEQ * DINNER) / 256, 256, 0, stream>>>(xz, conv_w, conv_b, u);

    // 3) ssm = u @ x_proj_w.T      (1024 x 2112, K=2048)
    gemm_tn_64<0><<<dim3(NPROJ / 64, L_SEQ / 64), 256, 0, stream>>>(
        u, x_proj_w, nullptr, ssm, L_SEQ, NPROJ, DINNER, DINNER);

    // 4) delta = softplus(ssm[:, :2048] @ dt_proj_w.T + dt_proj_b)   (1024 x 2048, K=2048, lda=2112)
    gemm_tn_64<1><<<dim3(DINNER / 64, L_SEQ / 64), 256, 0, stream>>>(
        ssm, dt_proj_w, dt_proj_b, delta, L_SEQ, DINNER, DINNER, NPROJ);

    // 5) sequential complex scan -> y (1024 x 2048), includes +D*u and *silu(z)
    scan_kernel<<<DINNER / 4, 64, 0, stream>>>(
        delta, ssm, u, xz, A_log_re, A_log_im, Dvec, y);

    // 6) out = y @ out_proj_w.T    (1024 x 1024, K=2048)
    gemm_tn_64<0><<<dim3(DMODEL / 64, L_SEQ / 64), 256, 0, stream>>>(
        y, out_proj_w, nullptr, out, L_SEQ, DMODEL, DINNER, DINNER);
}

// Round 8
// 893.257 us; speedup vs baseline: 1.8986x; 1.8986x over previous
//
#include <hip/hip_runtime.h>
#include <hip/hip_bf16.h>
#include <math.h>

// Problem constants
#define L_SEQ   1024
#define DMODEL  1024
#define DINNER  2048
#define DSTATE  16
#define DCONV   4
#define NPROJ   (DINNER + 4 * DSTATE)   // 2112
#define NCHUNK  16
#define CHUNK   64                       // L_SEQ / NCHUNK
#define NDN     (DINNER * DSTATE)        // 32768 (d,n) pairs

__device__ __forceinline__ float softplus_f(float v) {
    return fmaxf(v, 0.f) + log1pf(expf(-fabsf(v)));
}
__device__ __forceinline__ float silu_f(float v) {
    return v / (1.f + expf(-v));
}

// -------- Tiled f32 GEMM: C[M,N] = A[M,K(lda)] @ W[N,K]^T (+bias,epi) ------------
// BM=128, BN=64, BK=16. 256 threads. Thread tile 8x4 (rows ty*4+i & 64+ty*4+i,
// cols tx*4+j). All LDS float4 reads bank-conflict-free. No edge guards:
// requires M%128==0, N%64==0, K%16==0 (true for all four GEMMs here).
// EPI: 0 = plain store, 1 = softplus(acc + bias[col])
template<int EPI>
__global__ __launch_bounds__(256) void gemm_tn_128x64(
    const float* __restrict__ A, const float* __restrict__ W,
    const float* __restrict__ bias, float* __restrict__ C,
    int M, int N, int K, int lda)
{
    __shared__ float As[16][128];
    __shared__ float Ws[16][64];
    const int tid = threadIdx.x;
    const int tx = tid & 15;        // col group
    const int ty = tid >> 4;        // row group 0..15
    const int row0 = blockIdx.y * 128;
    const int col0 = blockIdx.x * 64;

    // staging indices
    const int sm = tid >> 1;            // 0..127 (A row)
    const int sk = (tid & 1) * 8;       // 0 or 8 (A k-offset)
    const int wn = tid >> 2;            // 0..63  (W row)
    const int wk = (tid & 3) * 4;       // 0,4,8,12 (W k-offset)

    float acc[8][4] = {};

    for (int k0 = 0; k0 < K; k0 += 16) {
        {
            const float* ap = &A[(size_t)(row0 + sm) * lda + (k0 + sk)];
            float4 a0 = *reinterpret_cast<const float4*>(ap);
            float4 a1 = *reinterpret_cast<const float4*>(ap + 4);
            As[sk + 0][sm] = a0.x; As[sk + 1][sm] = a0.y;
            As[sk + 2][sm] = a0.z; As[sk + 3][sm] = a0.w;
            As[sk + 4][sm] = a1.x; As[sk + 5][sm] = a1.y;
            As[sk + 6][sm] = a1.z; As[sk + 7][sm] = a1.w;
            const float* wp = &W[(size_t)(col0 + wn) * K + (k0 + wk)];
            float4 w0 = *reinterpret_cast<const float4*>(wp);
            Ws[wk + 0][wn] = w0.x; Ws[wk + 1][wn] = w0.y;
            Ws[wk + 2][wn] = w0.z; Ws[wk + 3][wn] = w0.w;
        }
        __syncthreads();
        #pragma unroll
        for (int k = 0; k < 16; ++k) {
            float4 a0 = *reinterpret_cast<const float4*>(&As[k][ty * 4]);
            float4 a1 = *reinterpret_cast<const float4*>(&As[k][64 + ty * 4]);
            float4 w0 = *reinterpret_cast<const float4*>(&Ws[k][tx * 4]);
            float av[8] = {a0.x, a0.y, a0.z, a0.w, a1.x, a1.y, a1.z, a1.w};
            float wv[4] = {w0.x, w0.y, w0.z, w0.w};
            #pragma unroll
            for (int i = 0; i < 8; ++i)
                #pragma unroll
                for (int j = 0; j < 4; ++j)
                    acc[i][j] = fmaf(av[i], wv[j], acc[i][j]);
        }
        __syncthreads();
    }

    #pragma unroll
    for (int i = 0; i < 8; ++i) {
        int row = row0 + ((i < 4) ? (ty * 4 + i) : (64 + ty * 4 + (i - 4)));
        int col = col0 + tx * 4;
        float4 v;
        float* vp = &v.x;
        #pragma unroll
        for (int j = 0; j < 4; ++j) {
            float t = acc[i][j];
            if (EPI == 1) {
                t += bias[col + j];
                t = softplus_f(t);
            }
            vp[j] = t;
        }
        *reinterpret_cast<float4*>(&C[(size_t)row * N + col]) = v;
    }
}

// -------- Depthwise causal conv (k=4) + bias + SiLU ------------------------------
__global__ __launch_bounds__(256) void conv_silu_kernel(
    const float* __restrict__ xz, const float* __restrict__ cw,
    const float* __restrict__ cb, float* __restrict__ u)
{
    int idx = blockIdx.x * 256 + threadIdx.x;
    int l = idx >> 11;
    int d = idx & (DINNER - 1);
    float acc = cb[d];
    #pragma unroll
    for (int k = 0; k < DCONV; ++k) {
        int ls = l - (DCONV - 1) + k;
        float xv = (ls >= 0) ? xz[(size_t)ls * (2 * DINNER) + d] : 0.f;
        acc = fmaf(xv, cw[d * DCONV + k], acc);
    }
    u[idx] = silu_f(acc);
}

// -------- Shared coefficient computation -----------------------------------------
__device__ __forceinline__ void bilinear_coef(
    float dt, float a_re, float a_im,
    float& ab_re, float& ab_im, float& co_re, float& co_im)
{
    float dta_re = dt * a_re, dta_im = dt * a_im;
    float den_re = 2.f - dta_re, den_im = -dta_im;
    float num_re = 2.f + dta_re, num_im = dta_im;
    float inv = 1.f / (den_re * den_re + den_im * den_im);
    ab_re = (num_re * den_re + num_im * den_im) * inv;
    ab_im = (num_im * den_re - num_re * den_im) * inv;
    float t = 2.f * dt * inv;
    co_re =  t * den_re;
    co_im = -t * den_im;
}

// -------- Chunked scan, pass 1: per-chunk (P, S) ---------------------------------
__global__ __launch_bounds__(64) void scan_chunk_kernel(
    const float* __restrict__ delta, const float* __restrict__ ssm,
    const float* __restrict__ u,
    const float* __restrict__ A_log_re, const float* __restrict__ A_log_im,
    float2* __restrict__ Pc, float2* __restrict__ Sc)
{
    const int b = blockIdx.x;
    const int chunk = b >> 9;
    const int d4 = b & 511;
    const int tid = threadIdx.x;
    const int n = tid & 15;
    const int dloc = tid >> 4;
    const int d = d4 * 4 + dloc;

    const float mag  = expf(A_log_re[d * DSTATE + n]);
    const float alim = A_log_im[d * DSTATE + n];
    const float a_re = -mag * cosf(alim);
    const float a_im = -mag * sinf(alim);

    float p_re = 1.f, p_im = 0.f;
    float s_re = 0.f, s_im = 0.f;

    const int l0 = chunk * CHUNK;
    #pragma unroll 4
    for (int i = 0; i < CHUNK; ++i) {
        const int l = l0 + i;
        float dt = delta[(size_t)l * DINNER + d];
        float uv = u[(size_t)l * DINNER + d];
        const float* srow = ssm + (size_t)l * NPROJ + DINNER;
        float br = srow[n];
        float bi = srow[DSTATE + n];

        float ab_re, ab_im, co_re, co_im;
        bilinear_coef(dt, a_re, a_im, ab_re, ab_im, co_re, co_im);
        float cbr = co_re * br - co_im * bi;
        float cbi = co_re * bi + co_im * br;
        float ub_re = cbr * uv;
        float ub_im = cbi * uv;

        float sr = ab_re * s_re - ab_im * s_im + ub_re;
        float si = ab_re * s_im + ab_im * s_re + ub_im;
        s_re = sr; s_im = si;
        float pr = ab_re * p_re - ab_im * p_im;
        float pi = ab_re * p_im + ab_im * p_re;
        p_re = pr; p_im = pi;
    }

    const int idx = chunk * NDN + d * DSTATE + n;
    Pc[idx] = make_float2(p_re, p_im);
    Sc[idx] = make_float2(s_re, s_im);
}

// -------- Chunked scan, pass 2: sequential combine over 16 chunks ----------------
// One thread per (d,n). Overwrites Pc[c] with the state ENTERING chunk c.
__global__ __launch_bounds__(256) void scan_combine_kernel(
    float2* __restrict__ Pc, const float2* __restrict__ Sc)
{
    const int td = blockIdx.x * 256 + threadIdx.x;   // 0..NDN-1
    float h_re = 0.f, h_im = 0.f;
    #pragma unroll
    for (int c = 0; c < NCHUNK; ++c) {
        float2 p = Pc[c * NDN + td];
        float2 s = Sc[c * NDN + td];
        Pc[c * NDN + td] = make_float2(h_re, h_im);   // state entering chunk c
        float nr = s.x + p.x * h_re - p.y * h_im;
        float ni = s.y + p.x * h_im + p.y * h_re;
        h_re = nr; h_im = ni;
    }
}

// -------- Chunked scan, pass 3: re-scan with correct H_in, emit y ----------------
__global__ __launch_bounds__(64) void scan_final_kernel(
    const float* __restrict__ delta, const float* __restrict__ ssm,
    const float* __restrict__ u, const float* __restrict__ xz,
    const float* __restrict__ A_log_re, const float* __restrict__ A_log_im,
    const float* __restrict__ Dvec, const float2* __restrict__ Hin,
    float* __restrict__ y)
{
    const int b = blockIdx.x;
    const int chunk = b >> 9;
    const int d4 = b & 511;
    const int tid = threadIdx.x;
    const int n = tid & 15;
    const int dloc = tid >> 4;
    const int d = d4 * 4 + dloc;

    const float mag  = expf(A_log_re[d * DSTATE + n]);
    const float alim = A_log_im[d * DSTATE + n];
    const float a_re = -mag * cosf(alim);
    const float a_im = -mag * sinf(alim);
    const float Dd   = Dvec[d];

    float2 h0 = Hin[chunk * NDN + d * DSTATE + n];
    float h_re = h0.x, h_im = h0.y;

    const int l0 = chunk * CHUNK;
    #pragma unroll 2
    for (int i = 0; i < CHUNK; ++i) {
        const int l = l0 + i;
        float dt = delta[(size_t)l * DINNER + d];
        float uv = u[(size_t)l * DINNER + d];
        const float* srow = ssm + (size_t)l * NPROJ + DINNER;
        float br = srow[n];
        float bi = srow[DSTATE + n];
        float cr = srow[2 * DSTATE + n];
        float ci = srow[3 * DSTATE + n];

        float ab_re, ab_im, co_re, co_im;
        bilinear_coef(dt, a_re, a_im, ab_re, ab_im, co_re, co_im);
        float cbr = co_re * br - co_im * bi;
        float cbi = co_re * bi + co_im * br;
        float ub_re = cbr * uv;
        float ub_im = cbi * uv;

        float hr = ab_re * h_re - ab_im * h_im + ub_re;
        float hi = ab_re * h_im + ab_im * h_re + ub_im;
        h_re = hr; h_im = hi;

        float contrib = cr * h_re - ci * h_im;
        contrib += __shfl_xor(contrib, 1, 16);
        contrib += __shfl_xor(contrib, 2, 16);
        contrib += __shfl_xor(contrib, 4, 16);
        contrib += __shfl_xor(contrib, 8, 16);
        if (n == 0) {
            float zv = xz[(size_t)l * (2 * DINNER) + DINNER + d];
            float yv = contrib + Dd * uv;
            y[(size_t)l * DINNER + d] = yv * silu_f(zv);
        }
    }
}

extern "C" void kernel_launch(void* const* d_in, const int* in_sizes, int n_in,
                              void* d_out, int out_size, void* d_ws, size_t ws_size,
                              hipStream_t stream)
{
    const float* x         = (const float*)d_in[0];
    const float* in_proj_w = (const float*)d_in[1];
    const float* conv_w    = (const float*)d_in[2];
    const float* conv_b    = (const float*)d_in[3];
    const float* x_proj_w  = (const float*)d_in[4];
    const float* dt_proj_w = (const float*)d_in[5];
    const float* dt_proj_b = (const float*)d_in[6];
    const float* A_log_re  = (const float*)d_in[7];
    const float* A_log_im  = (const float*)d_in[8];
    const float* Dvec      = (const float*)d_in[9];
    const float* out_proj_w= (const float*)d_in[10];
    float* out = (float*)d_out;

    float* ws    = (float*)d_ws;
    float* xz    = ws;                                    // 4,194,304 floats
    float* u     = xz    + (size_t)L_SEQ * 2 * DINNER;    // 2,097,152
    float* ssm   = u     + (size_t)L_SEQ * DINNER;        // 2,162,688
    float* delta = ssm   + (size_t)L_SEQ * NPROJ;         // 2,097,152
    float* y     = delta + (size_t)L_SEQ * DINNER;        // 2,097,152
    float2* Pc   = (float2*)(y + (size_t)L_SEQ * DINNER); // 1,048,576 floats
    float2* Sc   = Pc + (size_t)NCHUNK * NDN;             // 1,048,576 floats

    // 1) xz = x @ in_proj_w.T      (1024 x 4096, K=1024)
    gemm_tn_128x64<0><<<dim3((2 * DINNER) / 64, L_SEQ / 128), 256, 0, stream>>>(
        x, in_proj_w, nullptr, xz, L_SEQ, 2 * DINNER, DMODEL, DMODEL);

    // 2) depthwise causal conv + SiLU -> u   (1024 x 2048)
    conv_silu_kernel<<<(L_SEQ * DINNER) / 256, 256, 0, stream>>>(xz, conv_w, conv_b, u);

    // 3) ssm = u @ x_proj_w.T      (1024 x 2112, K=2048)   2112 = 33*64
    gemm_tn_128x64<0><<<dim3(NPROJ / 64, L_SEQ / 128), 256, 0, stream>>>(
        u, x_proj_w, nullptr, ssm, L_SEQ, NPROJ, DINNER, DINNER);

    // 4) delta = softplus(ssm[:, :2048] @ dt_proj_w.T + dt_proj_b)
    gemm_tn_128x64<1><<<dim3(DINNER / 64, L_SEQ / 128), 256, 0, stream>>>(
        ssm, dt_proj_w, dt_proj_b, delta, L_SEQ, DINNER, DINNER, NPROJ);

    // 5) chunk-parallel complex scan -> y
    scan_chunk_kernel<<<(DINNER / 4) * NCHUNK, 64, 0, stream>>>(
        delta, ssm, u, A_log_re, A_log_im, Pc, Sc);
    scan_combine_kernel<<<NDN / 256, 256, 0, stream>>>(Pc, Sc);
    scan_final_kernel<<<(DINNER / 4) * NCHUNK, 64, 0, stream>>>(
        delta, ssm, u, xz, A_log_re, A_log_im, Dvec, Pc, y);

    // 6) out = y @ out_proj_w.T    (1024 x 1024, K=2048)
    gemm_tn_128x64<0><<<dim3(DMODEL / 64, L_SEQ / 128), 256, 0, stream>>>(
        y, out_proj_w, nullptr, out, L_SEQ, DMODEL, DINNER, DINNER);
}

// Round 12
// 542.373 us; speedup vs baseline: 3.1270x; 1.6469x over previous
//
#include <hip/hip_runtime.h>
#include <hip/hip_bf16.h>
#include <math.h>

// Problem constants
#define L_SEQ   1024
#define DMODEL  1024
#define DINNER  2048
#define DSTATE  16
#define DCONV   4
#define NPROJ   (DINNER + 4 * DSTATE)   // 2112
#define NCHUNK  16
#define CHUNK   64                       // L_SEQ / NCHUNK
#define NDN     (DINNER * DSTATE)        // 32768 (d,n) pairs

typedef __attribute__((ext_vector_type(8))) short  short8;
typedef __attribute__((ext_vector_type(4))) float  f32x4;
typedef __attribute__((ext_vector_type(4))) unsigned short us4;

__device__ __forceinline__ float softplus_f(float v) {
    return fmaxf(v, 0.f) + log1pf(expf(-fabsf(v)));
}
__device__ __forceinline__ float silu_f(float v) {
    return v / (1.f + expf(-v));
}

// Split f32 into bf16 hi (truncated) + bf16 lo (rounded residual).
// x ≈ hi + lo with relative error ~2^-17.
__device__ __forceinline__ void split4(float4 v, us4& h, us4& l) {
    float vv[4] = {v.x, v.y, v.z, v.w};
    #pragma unroll
    for (int i = 0; i < 4; ++i) {
        unsigned b  = __float_as_uint(vv[i]);
        unsigned hb = b & 0xffff0000u;
        float    r  = vv[i] - __uint_as_float(hb);   // exact
        unsigned rb = __float_as_uint(r) + 0x8000u;  // rne-ish
        h[i] = (unsigned short)(hb >> 16);
        l[i] = (unsigned short)(rb >> 16);
    }
}

// -------- MFMA split-bf16 GEMM: C[M,N] = A[M,K(lda)] @ W[N,K]^T (+bias,epi) -----
// BM in {128,64}, BN=64, BK=32. 256 threads = 4 waves in 2x2.
// Wave tile: (BM/2) x 32  ->  MF = BM/32 frags in M, NF = 2 frags in N.
// acc = Ahi*Whi + Ahi*Wlo + Alo*Whi  (3 MFMAs per frag pair, f32 accumulate).
// LDS rows padded to 40 ushorts (80B) -> conflict-free ds_read_b128 frags.
// Requires M%BM==0, N%64==0, K%32==0 (true for all four GEMMs).
// EPI: 0 = plain store, 1 = softplus(acc + bias[col])
template<int BM, int EPI>
__global__ __launch_bounds__(256) void gemm_mfma(
    const float* __restrict__ A, const float* __restrict__ W,
    const float* __restrict__ bias, float* __restrict__ C,
    int M, int N, int K, int lda)
{
    constexpr int MF = BM / 32;     // 4 (BM=128) or 2 (BM=64)
    constexpr int NF = 2;
    __shared__ unsigned short sAh[BM * 40], sAl[BM * 40];
    __shared__ unsigned short sBh[64 * 40], sBl[64 * 40];

    const int tid  = threadIdx.x;
    const int w    = tid >> 6;
    const int lane = tid & 63;
    const int wr   = w >> 1;            // wave row 0..1
    const int wc   = w & 1;             // wave col 0..1
    const int lrow = lane & 15;         // row/col within fragment
    const int lkb  = lane >> 4;         // k-block 0..3
    const int row0 = blockIdx.y * BM;
    const int col0 = blockIdx.x * 64;

    // staging: 8 threads per 32-k row, one float4 each
    const int srow = tid >> 3;          // 0..31
    const int sfq  = tid & 7;           // float4 index

    f32x4 acc[MF][NF];
    #pragma unroll
    for (int m = 0; m < MF; ++m)
        #pragma unroll
        for (int n = 0; n < NF; ++n)
            acc[m][n] = (f32x4){0.f, 0.f, 0.f, 0.f};

    for (int k0 = 0; k0 < K; k0 += 32) {
        // ---- stage A (BM rows x 32 k) ----
        #pragma unroll
        for (int p = 0; p < BM / 32; ++p) {
            int r = srow + p * 32;
            float4 v = *reinterpret_cast<const float4*>(
                A + (size_t)(row0 + r) * lda + k0 + sfq * 4);
            us4 h, l;
            split4(v, h, l);
            *reinterpret_cast<us4*>(sAh + r * 40 + sfq * 4) = h;
            *reinterpret_cast<us4*>(sAl + r * 40 + sfq * 4) = l;
        }
        // ---- stage W (64 rows x 32 k) ----
        #pragma unroll
        for (int p = 0; p < 2; ++p) {
            int r = srow + p * 32;
            float4 v = *reinterpret_cast<const float4*>(
                W + (size_t)(col0 + r) * K + k0 + sfq * 4);
            us4 h, l;
            split4(v, h, l);
            *reinterpret_cast<us4*>(sBh + r * 40 + sfq * 4) = h;
            *reinterpret_cast<us4*>(sBl + r * 40 + sfq * 4) = l;
        }
        __syncthreads();

        // ---- fragment loads ----
        short8 ah[MF], al[MF], bh[NF], bl[NF];
        #pragma unroll
        for (int m = 0; m < MF; ++m) {
            int off = (wr * (BM / 2) + m * 16 + lrow) * 40 + lkb * 8;
            ah[m] = *reinterpret_cast<const short8*>(sAh + off);
            al[m] = *reinterpret_cast<const short8*>(sAl + off);
        }
        #pragma unroll
        for (int n = 0; n < NF; ++n) {
            int off = (wc * 32 + n * 16 + lrow) * 40 + lkb * 8;
            bh[n] = *reinterpret_cast<const short8*>(sBh + off);
            bl[n] = *reinterpret_cast<const short8*>(sBl + off);
        }

        // ---- MFMA: hi*hi + hi*lo + lo*hi ----
        #pragma unroll
        for (int m = 0; m < MF; ++m)
            #pragma unroll
            for (int n = 0; n < NF; ++n) {
                acc[m][n] = __builtin_amdgcn_mfma_f32_16x16x32_bf16(
                    ah[m], bh[n], acc[m][n], 0, 0, 0);
                acc[m][n] = __builtin_amdgcn_mfma_f32_16x16x32_bf16(
                    ah[m], bl[n], acc[m][n], 0, 0, 0);
                acc[m][n] = __builtin_amdgcn_mfma_f32_16x16x32_bf16(
                    al[m], bh[n], acc[m][n], 0, 0, 0);
            }
        __syncthreads();
    }

    // ---- epilogue: D[row=(lane>>4)*4+r][col=lane&15] per fragment ----
    #pragma unroll
    for (int m = 0; m < MF; ++m)
        #pragma unroll
        for (int n = 0; n < NF; ++n) {
            int gr0 = row0 + wr * (BM / 2) + m * 16 + lkb * 4;
            int gc  = col0 + wc * 32 + n * 16 + lrow;
            #pragma unroll
            for (int r = 0; r < 4; ++r) {
                float v = acc[m][n][r];
                if (EPI == 1) v = softplus_f(v + bias[gc]);
                C[(size_t)(gr0 + r) * N + gc] = v;
            }
        }
}

// -------- Depthwise causal conv (k=4) + bias + SiLU ------------------------------
__global__ __launch_bounds__(256) void conv_silu_kernel(
    const float* __restrict__ xz, const float* __restrict__ cw,
    const float* __restrict__ cb, float* __restrict__ u)
{
    int idx = blockIdx.x * 256 + threadIdx.x;
    int l = idx >> 11;
    int d = idx & (DINNER - 1);
    float acc = cb[d];
    #pragma unroll
    for (int k = 0; k < DCONV; ++k) {
        int ls = l - (DCONV - 1) + k;
        float xv = (ls >= 0) ? xz[(size_t)ls * (2 * DINNER) + d] : 0.f;
        acc = fmaf(xv, cw[d * DCONV + k], acc);
    }
    u[idx] = silu_f(acc);
}

// -------- Shared coefficient computation -----------------------------------------
__device__ __forceinline__ void bilinear_coef(
    float dt, float a_re, float a_im,
    float& ab_re, float& ab_im, float& co_re, float& co_im)
{
    float dta_re = dt * a_re, dta_im = dt * a_im;
    float den_re = 2.f - dta_re, den_im = -dta_im;
    float num_re = 2.f + dta_re, num_im = dta_im;
    float inv = 1.f / (den_re * den_re + den_im * den_im);
    ab_re = (num_re * den_re + num_im * den_im) * inv;
    ab_im = (num_im * den_re - num_re * den_im) * inv;
    float t = 2.f * dt * inv;
    co_re =  t * den_re;
    co_im = -t * den_im;
}

// -------- Chunked scan, pass 1: per-chunk (P, S) ---------------------------------
__global__ __launch_bounds__(64) void scan_chunk_kernel(
    const float* __restrict__ delta, const float* __restrict__ ssm,
    const float* __restrict__ u,
    const float* __restrict__ A_log_re, const float* __restrict__ A_log_im,
    float2* __restrict__ Pc, float2* __restrict__ Sc)
{
    const int b = blockIdx.x;
    const int chunk = b >> 9;
    const int d4 = b & 511;
    const int tid = threadIdx.x;
    const int n = tid & 15;
    const int dloc = tid >> 4;
    const int d = d4 * 4 + dloc;

    const float mag  = expf(A_log_re[d * DSTATE + n]);
    const float alim = A_log_im[d * DSTATE + n];
    const float a_re = -mag * cosf(alim);
    const float a_im = -mag * sinf(alim);

    float p_re = 1.f, p_im = 0.f;
    float s_re = 0.f, s_im = 0.f;

    const int l0 = chunk * CHUNK;
    #pragma unroll 4
    for (int i = 0; i < CHUNK; ++i) {
        const int l = l0 + i;
        float dt = delta[(size_t)l * DINNER + d];
        float uv = u[(size_t)l * DINNER + d];
        const float* srow = ssm + (size_t)l * NPROJ + DINNER;
        float br = srow[n];
        float bi = srow[DSTATE + n];

        float ab_re, ab_im, co_re, co_im;
        bilinear_coef(dt, a_re, a_im, ab_re, ab_im, co_re, co_im);
        float cbr = co_re * br - co_im * bi;
        float cbi = co_re * bi + co_im * br;
        float ub_re = cbr * uv;
        float ub_im = cbi * uv;

        float sr = ab_re * s_re - ab_im * s_im + ub_re;
        float si = ab_re * s_im + ab_im * s_re + ub_im;
        s_re = sr; s_im = si;
        float pr = ab_re * p_re - ab_im * p_im;
        float pi = ab_re * p_im + ab_im * p_re;
        p_re = pr; p_im = pi;
    }

    const int idx = chunk * NDN + d * DSTATE + n;
    Pc[idx] = make_float2(p_re, p_im);
    Sc[idx] = make_float2(s_re, s_im);
}

// -------- Chunked scan, pass 2: sequential combine over 16 chunks ----------------
// One thread per (d,n). Overwrites Pc[c] with the state ENTERING chunk c.
__global__ __launch_bounds__(256) void scan_combine_kernel(
    float2* __restrict__ Pc, const float2* __restrict__ Sc)
{
    const int td = blockIdx.x * 256 + threadIdx.x;   // 0..NDN-1
    float h_re = 0.f, h_im = 0.f;
    #pragma unroll
    for (int c = 0; c < NCHUNK; ++c) {
        float2 p = Pc[c * NDN + td];
        float2 s = Sc[c * NDN + td];
        Pc[c * NDN + td] = make_float2(h_re, h_im);   // state entering chunk c
        float nr = s.x + p.x * h_re - p.y * h_im;
        float ni = s.y + p.x * h_im + p.y * h_re;
        h_re = nr; h_im = ni;
    }
}

// -------- Chunked scan, pass 3: re-scan with correct H_in, emit y ----------------
__global__ __launch_bounds__(64) void scan_final_kernel(
    const float* __restrict__ delta, const float* __restrict__ ssm,
    const float* __restrict__ u, const float* __restrict__ xz,
    const float* __restrict__ A_log_re, const float* __restrict__ A_log_im,
    const float* __restrict__ Dvec, const float2* __restrict__ Hin,
    float* __restrict__ y)
{
    const int b = blockIdx.x;
    const int chunk = b >> 9;
    const int d4 = b & 511;
    const int tid = threadIdx.x;
    const int n = tid & 15;
    const int dloc = tid >> 4;
    const int d = d4 * 4 + dloc;

    const float mag  = expf(A_log_re[d * DSTATE + n]);
    const float alim = A_log_im[d * DSTATE + n];
    const float a_re = -mag * cosf(alim);
    const float a_im = -mag * sinf(alim);
    const float Dd   = Dvec[d];

    float2 h0 = Hin[chunk * NDN + d * DSTATE + n];
    float h_re = h0.x, h_im = h0.y;

    const int l0 = chunk * CHUNK;
    #pragma unroll 2
    for (int i = 0; i < CHUNK; ++i) {
        const int l = l0 + i;
        float dt = delta[(size_t)l * DINNER + d];
        float uv = u[(size_t)l * DINNER + d];
        const float* srow = ssm + (size_t)l * NPROJ + DINNER;
        float br = srow[n];
        float bi = srow[DSTATE + n];
        float cr = srow[2 * DSTATE + n];
        float ci = srow[3 * DSTATE + n];

        float ab_re, ab_im, co_re, co_im;
        bilinear_coef(dt, a_re, a_im, ab_re, ab_im, co_re, co_im);
        float cbr = co_re * br - co_im * bi;
        float cbi = co_re * bi + co_im * br;
        float ub_re = cbr * uv;
        float ub_im = cbi * uv;

        float hr = ab_re * h_re - ab_im * h_im + ub_re;
        float hi = ab_re * h_im + ab_im * h_re + ub_im;
        h_re = hr; h_im = hi;

        float contrib = cr * h_re - ci * h_im;
        contrib += __shfl_xor(contrib, 1, 16);
        contrib += __shfl_xor(contrib, 2, 16);
        contrib += __shfl_xor(contrib, 4, 16);
        contrib += __shfl_xor(contrib, 8, 16);
        if (n == 0) {
            float zv = xz[(size_t)l * (2 * DINNER) + DINNER + d];
            float yv = contrib + Dd * uv;
            y[(size_t)l * DINNER + d] = yv * silu_f(zv);
        }
    }
}

extern "C" void kernel_launch(void* const* d_in, const int* in_sizes, int n_in,
                              void* d_out, int out_size, void* d_ws, size_t ws_size,
                              hipStream_t stream)
{
    const float* x         = (const float*)d_in[0];
    const float* in_proj_w = (const float*)d_in[1];
    const float* conv_w    = (const float*)d_in[2];
    const float* conv_b    = (const float*)d_in[3];
    const float* x_proj_w  = (const float*)d_in[4];
    const float* dt_proj_w = (const float*)d_in[5];
    const float* dt_proj_b = (const float*)d_in[6];
    const float* A_log_re  = (const float*)d_in[7];
    const float* A_log_im  = (const float*)d_in[8];
    const float* Dvec      = (const float*)d_in[9];
    const float* out_proj_w= (const float*)d_in[10];
    float* out = (float*)d_out;

    float* ws    = (float*)d_ws;
    float* xz    = ws;                                    // 4,194,304 floats
    float* u     = xz    + (size_t)L_SEQ * 2 * DINNER;    // 2,097,152
    float* ssm   = u     + (size_t)L_SEQ * DINNER;        // 2,162,688
    float* delta = ssm   + (size_t)L_SEQ * NPROJ;         // 2,097,152
    float* y     = delta + (size_t)L_SEQ * DINNER;        // 2,097,152
    float2* Pc   = (float2*)(y + (size_t)L_SEQ * DINNER); // 1,048,576 floats
    float2* Sc   = Pc + (size_t)NCHUNK * NDN;             // 1,048,576 floats

    // 1) xz = x @ in_proj_w.T      (1024 x 4096, K=1024)
    gemm_mfma<128, 0><<<dim3((2 * DINNER) / 64, L_SEQ / 128), 256, 0, stream>>>(
        x, in_proj_w, nullptr, xz, L_SEQ, 2 * DINNER, DMODEL, DMODEL);

    // 2) depthwise causal conv + SiLU -> u   (1024 x 2048)
    conv_silu_kernel<<<(L_SEQ * DINNER) / 256, 256, 0, stream>>>(xz, conv_w, conv_b, u);

    // 3) ssm = u @ x_proj_w.T      (1024 x 2112, K=2048)
    gemm_mfma<128, 0><<<dim3(NPROJ / 64, L_SEQ / 128), 256, 0, stream>>>(
        u, x_proj_w, nullptr, ssm, L_SEQ, NPROJ, DINNER, DINNER);

    // 4) delta = softplus(ssm[:, :2048] @ dt_proj_w.T + dt_proj_b)
    gemm_mfma<128, 1><<<dim3(DINNER / 64, L_SEQ / 128), 256, 0, stream>>>(
        ssm, dt_proj_w, dt_proj_b, delta, L_SEQ, DINNER, DINNER, NPROJ);

    // 5) chunk-parallel complex scan -> y
    scan_chunk_kernel<<<(DINNER / 4) * NCHUNK, 64, 0, stream>>>(
        delta, ssm, u, A_log_re, A_log_im, Pc, Sc);
    scan_combine_kernel<<<NDN / 256, 256, 0, stream>>>(Pc, Sc);
    scan_final_kernel<<<(DINNER / 4) * NCHUNK, 64, 0, stream>>>(
        delta, ssm, u, xz, A_log_re, A_log_im, Dvec, Pc, y);

    // 6) out = y @ out_proj_w.T    (1024 x 1024, K=2048)  -- BM=64 for 256 blocks
    gemm_mfma<64, 0><<<dim3(DMODEL / 64, L_SEQ / 64), 256, 0, stream>>>(
        y, out_proj_w, nullptr, out, L_SEQ, DMODEL, DINNER, DINNER);
}

// Round 13
// 420.302 us; speedup vs baseline: 4.0352x; 1.2904x over previous
//
#include <hip/hip_runtime.h>
#include <hip/hip_bf16.h>
#include <math.h>

// Problem constants
#define L_SEQ   1024
#define DMODEL  1024
#define DINNER  2048
#define DSTATE  16
#define DCONV   4
#define NPROJ   (DINNER + 4 * DSTATE)   // 2112
#define NCHUNK  16
#define CHUNK   64                       // L_SEQ / NCHUNK
#define NDN     (DINNER * DSTATE)        // 32768 (d,n) pairs

typedef __attribute__((ext_vector_type(8))) short  short8;
typedef __attribute__((ext_vector_type(4))) float  f32x4;
typedef __attribute__((ext_vector_type(4))) unsigned short us4;

__device__ __forceinline__ float softplus_f(float v) {
    return fmaxf(v, 0.f) + log1pf(expf(-fabsf(v)));
}
__device__ __forceinline__ float silu_f(float v) {
    return v * __builtin_amdgcn_rcpf(1.f + expf(-v));
}

// Split f32 into bf16 hi (truncated) + bf16 lo (rounded residual).
__device__ __forceinline__ void split4(float4 v, us4& h, us4& l) {
    float vv[4] = {v.x, v.y, v.z, v.w};
    #pragma unroll
    for (int i = 0; i < 4; ++i) {
        unsigned b  = __float_as_uint(vv[i]);
        unsigned hb = b & 0xffff0000u;
        float    r  = vv[i] - __uint_as_float(hb);   // exact
        unsigned rb = __float_as_uint(r) + 0x8000u;  // rne-ish
        h[i] = (unsigned short)(hb >> 16);
        l[i] = (unsigned short)(rb >> 16);
    }
}

// -------- MFMA split-bf16 split-K GEMM ------------------------------------------
// Cp[kz][M][N] = A[M, kslice(lda)] @ W[N, kslice]^T  (f32 partials, no epilogue)
// BM in {128,64}, BN=64, BK=32. 256 threads = 4 waves (2x2).
// K-slice per block: [blockIdx.z*K/gridDim.z, +K/gridDim.z)
template<int BM>
__global__ __launch_bounds__(256) void gemm_mfma_sk(
    const float* __restrict__ A, const float* __restrict__ W,
    float* __restrict__ Cp, int M, int N, int K, int lda)
{
    constexpr int MF = BM / 32;
    constexpr int NF = 2;
    __shared__ unsigned short sAh[BM * 40], sAl[BM * 40];
    __shared__ unsigned short sBh[64 * 40], sBl[64 * 40];

    const int tid  = threadIdx.x;
    const int w    = tid >> 6;
    const int lane = tid & 63;
    const int wr   = w >> 1;
    const int wc   = w & 1;
    const int lrow = lane & 15;
    const int lkb  = lane >> 4;
    const int row0 = blockIdx.y * BM;
    const int col0 = blockIdx.x * 64;

    const int KS   = K / gridDim.z;
    const int kbeg = blockIdx.z * KS;
    const int kend = kbeg + KS;

    const int srow = tid >> 3;
    const int sfq  = tid & 7;

    f32x4 acc[MF][NF];
    #pragma unroll
    for (int m = 0; m < MF; ++m)
        #pragma unroll
        for (int n = 0; n < NF; ++n)
            acc[m][n] = (f32x4){0.f, 0.f, 0.f, 0.f};

    for (int k0 = kbeg; k0 < kend; k0 += 32) {
        #pragma unroll
        for (int p = 0; p < BM / 32; ++p) {
            int r = srow + p * 32;
            float4 v = *reinterpret_cast<const float4*>(
                A + (size_t)(row0 + r) * lda + k0 + sfq * 4);
            us4 h, l;
            split4(v, h, l);
            *reinterpret_cast<us4*>(sAh + r * 40 + sfq * 4) = h;
            *reinterpret_cast<us4*>(sAl + r * 40 + sfq * 4) = l;
        }
        #pragma unroll
        for (int p = 0; p < 2; ++p) {
            int r = srow + p * 32;
            float4 v = *reinterpret_cast<const float4*>(
                W + (size_t)(col0 + r) * K + k0 + sfq * 4);
            us4 h, l;
            split4(v, h, l);
            *reinterpret_cast<us4*>(sBh + r * 40 + sfq * 4) = h;
            *reinterpret_cast<us4*>(sBl + r * 40 + sfq * 4) = l;
        }
        __syncthreads();

        short8 ah[MF], al[MF], bh[NF], bl[NF];
        #pragma unroll
        for (int m = 0; m < MF; ++m) {
            int off = (wr * (BM / 2) + m * 16 + lrow) * 40 + lkb * 8;
            ah[m] = *reinterpret_cast<const short8*>(sAh + off);
            al[m] = *reinterpret_cast<const short8*>(sAl + off);
        }
        #pragma unroll
        for (int n = 0; n < NF; ++n) {
            int off = (wc * 32 + n * 16 + lrow) * 40 + lkb * 8;
            bh[n] = *reinterpret_cast<const short8*>(sBh + off);
            bl[n] = *reinterpret_cast<const short8*>(sBl + off);
        }

        #pragma unroll
        for (int m = 0; m < MF; ++m)
            #pragma unroll
            for (int n = 0; n < NF; ++n) {
                acc[m][n] = __builtin_amdgcn_mfma_f32_16x16x32_bf16(
                    ah[m], bh[n], acc[m][n], 0, 0, 0);
                acc[m][n] = __builtin_amdgcn_mfma_f32_16x16x32_bf16(
                    ah[m], bl[n], acc[m][n], 0, 0, 0);
                acc[m][n] = __builtin_amdgcn_mfma_f32_16x16x32_bf16(
                    al[m], bh[n], acc[m][n], 0, 0, 0);
            }
        __syncthreads();
    }

    float* Cb = Cp + (size_t)blockIdx.z * M * N;
    #pragma unroll
    for (int m = 0; m < MF; ++m)
        #pragma unroll
        for (int n = 0; n < NF; ++n) {
            int gr0 = row0 + wr * (BM / 2) + m * 16 + lkb * 4;
            int gc  = col0 + wc * 32 + n * 16 + lrow;
            #pragma unroll
            for (int r = 0; r < 4; ++r)
                Cb[(size_t)(gr0 + r) * N + gc] = acc[m][n][r];
        }
}

// -------- Split-K reduction (+optional softplus(bias) epilogue) ------------------
// EPI: 0 = plain sum, 1 = softplus(sum + bias[col])
template<int EPI>
__global__ __launch_bounds__(256) void reduce_splitk(
    const float* __restrict__ part, float* __restrict__ out,
    const float* __restrict__ bias, int size, int N, int nsplit)
{
    int i = (blockIdx.x * 256 + threadIdx.x) * 4;
    if (i >= size) return;
    float4 s = *reinterpret_cast<const float4*>(part + i);
    for (int p = 1; p < nsplit; ++p) {
        float4 v = *reinterpret_cast<const float4*>(part + (size_t)p * size + i);
        s.x += v.x; s.y += v.y; s.z += v.z; s.w += v.w;
    }
    if (EPI == 1) {
        int col = i % N;
        float4 b = *reinterpret_cast<const float4*>(bias + col);
        s.x = softplus_f(s.x + b.x); s.y = softplus_f(s.y + b.y);
        s.z = softplus_f(s.z + b.z); s.w = softplus_f(s.w + b.w);
    }
    *reinterpret_cast<float4*>(out + i) = s;
}

// -------- Depthwise causal conv (k=4) + bias + SiLU ------------------------------
__global__ __launch_bounds__(256) void conv_silu_kernel(
    const float* __restrict__ xz, const float* __restrict__ cw,
    const float* __restrict__ cb, float* __restrict__ u)
{
    int idx = blockIdx.x * 256 + threadIdx.x;
    int l = idx >> 11;
    int d = idx & (DINNER - 1);
    float acc = cb[d];
    #pragma unroll
    for (int k = 0; k < DCONV; ++k) {
        int ls = l - (DCONV - 1) + k;
        float xv = (ls >= 0) ? xz[(size_t)ls * (2 * DINNER) + d] : 0.f;
        acc = fmaf(xv, cw[d * DCONV + k], acc);
    }
    u[idx] = silu_f(acc);
}

// -------- Bilinear coefficients, slim form ---------------------------------------
// den = 2 - dt*A;  A_bar = 4/den - 1;  coef = 2*dt/den.  One rcp, shared.
__device__ __forceinline__ void bilinear_coef(
    float dt, float a_re, float a_im,
    float& ab_re, float& ab_im, float& co_re, float& co_im)
{
    float dre = fmaf(-dt, a_re, 2.f);
    float dim = -dt * a_im;
    float inv = __builtin_amdgcn_rcpf(fmaf(dre, dre, dim * dim));
    float qre = dre * inv;          // Re(1/den)
    float qim = -dim * inv;         // Im(1/den)
    ab_re = fmaf(4.f, qre, -1.f);
    ab_im = 4.f * qim;
    float t2 = dt + dt;
    co_re = t2 * qre;
    co_im = t2 * qim;
}

// -------- Chunked scan, pass 1: per-chunk (P, S) ---------------------------------
__global__ __launch_bounds__(64) void scan_chunk_kernel(
    const float* __restrict__ delta, const float* __restrict__ ssm,
    const float* __restrict__ u,
    const float* __restrict__ A_log_re, const float* __restrict__ A_log_im,
    float2* __restrict__ Pc, float2* __restrict__ Sc)
{
    const int b = blockIdx.x;
    const int chunk = b >> 9;
    const int d4 = b & 511;
    const int tid = threadIdx.x;
    const int n = tid & 15;
    const int dloc = tid >> 4;
    const int d = d4 * 4 + dloc;

    const float mag  = expf(A_log_re[d * DSTATE + n]);
    const float alim = A_log_im[d * DSTATE + n];
    const float a_re = -mag * cosf(alim);
    const float a_im = -mag * sinf(alim);

    float p_re = 1.f, p_im = 0.f;
    float s_re = 0.f, s_im = 0.f;

    const int l0 = chunk * CHUNK;
    #pragma unroll 4
    for (int i = 0; i < CHUNK; ++i) {
        const int l = l0 + i;
        float dt = delta[(size_t)l * DINNER + d];
        float uv = u[(size_t)l * DINNER + d];
        const float* srow = ssm + (size_t)l * NPROJ + DINNER;
        float br = srow[n];
        float bi = srow[DSTATE + n];

        float ab_re, ab_im, co_re, co_im;
        bilinear_coef(dt, a_re, a_im, ab_re, ab_im, co_re, co_im);
        float cbr = co_re * br - co_im * bi;
        float cbi = co_re * bi + co_im * br;
        float ub_re = cbr * uv;
        float ub_im = cbi * uv;

        float sr = ab_re * s_re - ab_im * s_im + ub_re;
        float si = ab_re * s_im + ab_im * s_re + ub_im;
        s_re = sr; s_im = si;
        float pr = ab_re * p_re - ab_im * p_im;
        float pi = ab_re * p_im + ab_im * p_re;
        p_re = pr; p_im = pi;
    }

    const int idx = chunk * NDN + d * DSTATE + n;
    Pc[idx] = make_float2(p_re, p_im);
    Sc[idx] = make_float2(s_re, s_im);
}

// -------- Chunked scan, pass 2: sequential combine over 16 chunks ----------------
// One thread per (d,n). Overwrites Pc[c] with the state ENTERING chunk c.
__global__ __launch_bounds__(256) void scan_combine_kernel(
    float2* __restrict__ Pc, const float2* __restrict__ Sc)
{
    const int td = blockIdx.x * 256 + threadIdx.x;   // 0..NDN-1
    float h_re = 0.f, h_im = 0.f;
    #pragma unroll
    for (int c = 0; c < NCHUNK; ++c) {
        float2 p = Pc[c * NDN + td];
        float2 s = Sc[c * NDN + td];
        Pc[c * NDN + td] = make_float2(h_re, h_im);
        float nr = s.x + p.x * h_re - p.y * h_im;
        float ni = s.y + p.x * h_im + p.y * h_re;
        h_re = nr; h_im = ni;
    }
}

// -------- Chunked scan, pass 3: re-scan with correct H_in, emit y ----------------
__global__ __launch_bounds__(64) void scan_final_kernel(
    const float* __restrict__ delta, const float* __restrict__ ssm,
    const float* __restrict__ u, const float* __restrict__ xz,
    const float* __restrict__ A_log_re, const float* __restrict__ A_log_im,
    const float* __restrict__ Dvec, const float2* __restrict__ Hin,
    float* __restrict__ y)
{
    const int b = blockIdx.x;
    const int chunk = b >> 9;
    const int d4 = b & 511;
    const int tid = threadIdx.x;
    const int n = tid & 15;
    const int dloc = tid >> 4;
    const int d = d4 * 4 + dloc;

    const float mag  = expf(A_log_re[d * DSTATE + n]);
    const float alim = A_log_im[d * DSTATE + n];
    const float a_re = -mag * cosf(alim);
    const float a_im = -mag * sinf(alim);
    const float Dd   = Dvec[d];

    float2 h0 = Hin[chunk * NDN + d * DSTATE + n];
    float h_re = h0.x, h_im = h0.y;

    const int l0 = chunk * CHUNK;
    #pragma unroll 2
    for (int i = 0; i < CHUNK; ++i) {
        const int l = l0 + i;
        float dt = delta[(size_t)l * DINNER + d];
        float uv = u[(size_t)l * DINNER + d];
        const float* srow = ssm + (size_t)l * NPROJ + DINNER;
        float br = srow[n];
        float bi = srow[DSTATE + n];
        float cr = srow[2 * DSTATE + n];
        float ci = srow[3 * DSTATE + n];

        float ab_re, ab_im, co_re, co_im;
        bilinear_coef(dt, a_re, a_im, ab_re, ab_im, co_re, co_im);
        float cbr = co_re * br - co_im * bi;
        float cbi = co_re * bi + co_im * br;
        float ub_re = cbr * uv;
        float ub_im = cbi * uv;

        float hr = ab_re * h_re - ab_im * h_im + ub_re;
        float hi = ab_re * h_im + ab_im * h_re + ub_im;
        h_re = hr; h_im = hi;

        float contrib = cr * h_re - ci * h_im;
        contrib += __shfl_xor(contrib, 1, 16);
        contrib += __shfl_xor(contrib, 2, 16);
        contrib += __shfl_xor(contrib, 4, 16);
        contrib += __shfl_xor(contrib, 8, 16);
        if (n == 0) {
            float zv = xz[(size_t)l * (2 * DINNER) + DINNER + d];
            float yv = contrib + Dd * uv;
            y[(size_t)l * DINNER + d] = yv * silu_f(zv);
        }
    }
}

extern "C" void kernel_launch(void* const* d_in, const int* in_sizes, int n_in,
                              void* d_out, int out_size, void* d_ws, size_t ws_size,
                              hipStream_t stream)
{
    const float* x         = (const float*)d_in[0];
    const float* in_proj_w = (const float*)d_in[1];
    const float* conv_w    = (const float*)d_in[2];
    const float* conv_b    = (const float*)d_in[3];
    const float* x_proj_w  = (const float*)d_in[4];
    const float* dt_proj_w = (const float*)d_in[5];
    const float* dt_proj_b = (const float*)d_in[6];
    const float* A_log_re  = (const float*)d_in[7];
    const float* A_log_im  = (const float*)d_in[8];
    const float* Dvec      = (const float*)d_in[9];
    const float* out_proj_w= (const float*)d_in[10];
    float* out = (float*)d_out;

    float* ws    = (float*)d_ws;
    float* xz    = ws;                                    // 4,194,304 floats
    float* u     = xz    + (size_t)L_SEQ * 2 * DINNER;    // 2,097,152
    float* ssm   = u     + (size_t)L_SEQ * DINNER;        // 2,162,688
    float* delta = ssm   + (size_t)L_SEQ * NPROJ;         // 2,097,152
    float* y     = delta + (size_t)L_SEQ * DINNER;        // 2,097,152
    float2* Pc   = (float2*)(y + (size_t)L_SEQ * DINNER); // 1,048,576 floats
    float2* Sc   = Pc + (size_t)NCHUNK * NDN;             // 1,048,576 floats
    float* part  = (float*)(Sc + (size_t)NCHUNK * NDN);   // 8,650,752 floats max

    // 1) xz = x @ in_proj_w.T   (1024 x 4096, K=1024, SK=2)
    gemm_mfma_sk<128><<<dim3((2 * DINNER) / 64, L_SEQ / 128, 2), 256, 0, stream>>>(
        x, in_proj_w, part, L_SEQ, 2 * DINNER, DMODEL, DMODEL);
    reduce_splitk<0><<<(L_SEQ * 2 * DINNER) / 1024, 256, 0, stream>>>(
        part, xz, nullptr, L_SEQ * 2 * DINNER, 2 * DINNER, 2);

    // 2) depthwise causal conv + SiLU -> u
    conv_silu_kernel<<<(L_SEQ * DINNER) / 256, 256, 0, stream>>>(xz, conv_w, conv_b, u);

    // 3) ssm = u @ x_proj_w.T   (1024 x 2112, K=2048, SK=4)
    gemm_mfma_sk<128><<<dim3(NPROJ / 64, L_SEQ / 128, 4), 256, 0, stream>>>(
        u, x_proj_w, part, L_SEQ, NPROJ, DINNER, DINNER);
    reduce_splitk<0><<<(L_SEQ * NPROJ) / 1024, 256, 0, stream>>>(
        part, ssm, nullptr, L_SEQ * NPROJ, NPROJ, 4);

    // 4) delta = softplus(ssm[:, :2048] @ dt_proj_w.T + dt_proj_b)  (SK=4)
    gemm_mfma_sk<128><<<dim3(DINNER / 64, L_SEQ / 128, 4), 256, 0, stream>>>(
        ssm, dt_proj_w, part, L_SEQ, DINNER, DINNER, NPROJ);
    reduce_splitk<1><<<(L_SEQ * DINNER) / 1024, 256, 0, stream>>>(
        part, delta, dt_proj_b, L_SEQ * DINNER, DINNER, 4);

    // 5) chunk-parallel complex scan -> y
    scan_chunk_kernel<<<(DINNER / 4) * NCHUNK, 64, 0, stream>>>(
        delta, ssm, u, A_log_re, A_log_im, Pc, Sc);
    scan_combine_kernel<<<NDN / 256, 256, 0, stream>>>(Pc, Sc);
    scan_final_kernel<<<(DINNER / 4) * NCHUNK, 64, 0, stream>>>(
        delta, ssm, u, xz, A_log_re, A_log_im, Dvec, Pc, y);

    // 6) out = y @ out_proj_w.T  (1024 x 1024, K=2048, BM=64, SK=4)
    gemm_mfma_sk<64><<<dim3(DMODEL / 64, L_SEQ / 64, 4), 256, 0, stream>>>(
        y, out_proj_w, part, L_SEQ, DMODEL, DINNER, DINNER);
    reduce_splitk<0><<<(L_SEQ * DMODEL) / 1024, 256, 0, stream>>>(
        part, out, nullptr, L_SEQ * DMODEL, DMODEL, 4);
}